// Round 4
// baseline (106.737 us; speedup 1.0000x reference)
//
#include <hip/hip_runtime.h>
#include <math.h>

#define TEMP 20.0f
#define OFFSET_SCALE 0.03f
#define OFFSET_REG_W 0.1f
#define WEIGHT_GAIN 5.0f
#define SM_SHIFT 90.0f   // fixed softmax shift: exp(20*p - 90); safe for p < ~8.9 sigma

// ---------------- fused fast path: compile-time W,H, last-block finisher ----------------

template<int W, int H, int CHUNKS, int TPB>
__global__ __launch_bounds__(TPB) void hl_fused(
    const float* __restrict__ pred, const float* __restrict__ tgt,
    const float* __restrict__ poff, const float* __restrict__ tcoord,
    float* __restrict__ out, float4* __restrict__ ws, int* __restrict__ cnt, int B) {
    constexpr int HW    = W * H;
    constexpr int CE    = HW / CHUNKS;      // elements per chunk (whole rows)
    constexpr int CF4   = CE / 4;
    constexpr int ITERS = CF4 / TPB;
    static_assert(CF4 % TPB == 0, "chunk must divide evenly");
    static_assert(CE % W == 0, "chunk must be whole rows");
    constexpr int NWAVES = TPB / 64;

    const int blk = blockIdx.x;
    const int b   = blk / CHUNKS;
    const int c   = blk % CHUNKS;
    const int tid = threadIdx.x;
    const float4* p4 = (const float4*)(pred + (size_t)b * HW + (size_t)c * CE);
    const float4* t4 = (const float4*)(tgt  + (size_t)b * HW + (size_t)c * CE);

    float s[4]  = {0.f, 0.f, 0.f, 0.f};
    float sx[4] = {0.f, 0.f, 0.f, 0.f};
    float sy[4] = {0.f, 0.f, 0.f, 0.f};
    float hm[4] = {0.f, 0.f, 0.f, 0.f};

#pragma unroll
    for (int it = 0; it < ITERS; ++it) {
        const int i = tid + it * TPB;
        float4 pv = p4[i];
        float4 tv = t4[i];
        const int f = i << 2;
        const float hf = (float)(c * (CE / W) + f / W);   // W constexpr -> magic multiply
        const float wf = (float)(f % W);
        float pe[4] = {pv.x, pv.y, pv.z, pv.w};
        float te[4] = {tv.x, tv.y, tv.z, tv.w};
#pragma unroll
        for (int k = 0; k < 4; ++k) {
            float d = pe[k] - te[k];
            hm[k] = fmaf(d * d, fmaf(WEIGHT_GAIN, te[k], 1.f), hm[k]);
            float e = __expf(fmaf(pe[k], TEMP, -SM_SHIFT));
            s[k] += e;
            sx[k] = fmaf(e, wf + (float)k, sx[k]);
            sy[k] = fmaf(e, hf, sy[k]);
        }
    }
    float S  = (s[0]  + s[1])  + (s[2]  + s[3]);
    float SX = (sx[0] + sx[1]) + (sx[2] + sx[3]);
    float SY = (sy[0] + sy[1]) + (sy[2] + sy[3]);
    float HM = (hm[0] + hm[1]) + (hm[2] + hm[3]);

#pragma unroll
    for (int off = 32; off > 0; off >>= 1) {
        S  += __shfl_xor(S,  off);
        SX += __shfl_xor(SX, off);
        SY += __shfl_xor(SY, off);
        HM += __shfl_xor(HM, off);
    }
    __shared__ float4 red[NWAVES];
    __shared__ int flag;
    const int wave = tid >> 6;
    if ((tid & 63) == 0) red[wave] = make_float4(S, SX, SY, HM);
    __syncthreads();
    if (tid == 0) {
        float4 a = red[0];
#pragma unroll
        for (int wv = 1; wv < NWAVES; ++wv) {
            float4 r = red[wv];
            a.x += r.x; a.y += r.y; a.z += r.z; a.w += r.w;
        }
        ws[c * B + b] = a;               // [chunk][batch] -> coalesced in finisher
        __threadfence();                 // release: partial visible device-wide
        flag = atomicAdd(cnt, 1);        // deterministic integer arrival counter
    }
    __syncthreads();
    if (flag != (int)gridDim.x - 1) return;

    // ---- last block: final reduction (fixed order -> deterministic) ----
    __threadfence();                     // acquire: see all partials
    float HMt = 0.f, CD = 0.f, OG = 0.f;
    for (int bb = tid; bb < B; bb += TPB) {
        float Ss = 0.f, SXs = 0.f, SYs = 0.f, hms = 0.f;
#pragma unroll
        for (int cc = 0; cc < CHUNKS; ++cc) {
            float4 r = ws[cc * B + bb];
            Ss += r.x; SXs += r.y; SYs += r.z; hms += r.w;
        }
        float x  = SXs / Ss / (float)W;
        float y  = SYs / Ss / (float)H;
        float o0 = poff[2 * bb], o1 = poff[2 * bb + 1];
        float dx = x + o0 * OFFSET_SCALE - tcoord[2 * bb];
        float dy = y + o1 * OFFSET_SCALE - tcoord[2 * bb + 1];
        CD += dx * dx + dy * dy;
        OG += o0 * o0 + o1 * o1;
        HMt += hms;
    }
#pragma unroll
    for (int off = 32; off > 0; off >>= 1) {
        HMt += __shfl_xor(HMt, off);
        CD  += __shfl_xor(CD,  off);
        OG  += __shfl_xor(OG,  off);
    }
    __shared__ float r3[NWAVES][3];
    if ((tid & 63) == 0) { r3[wave][0] = HMt; r3[wave][1] = CD; r3[wave][2] = OG; }
    __syncthreads();
    if (tid == 0) {
        float hmT = 0.f, cdT = 0.f, ogT = 0.f;
#pragma unroll
        for (int wv = 0; wv < NWAVES; ++wv) {
            hmT += r3[wv][0]; cdT += r3[wv][1]; ogT += r3[wv][2];
        }
        float HWf = (float)W * (float)H;
        float heatmap_loss = hmT / ((float)B * HWf);
        float coord_loss   = cdT / ((float)B * 2.f);
        float offset_reg   = ogT / ((float)B * 2.f) * OFFSET_REG_W;
        out[0] = heatmap_loss + 2.0f * coord_loss + offset_reg;
        out[1] = heatmap_loss;
        out[2] = coord_loss;
    }
}

// ---------------- generic fallback (online softmax, runtime shapes) ----------------

__device__ __forceinline__ void sm_combine(float& m, float& s, float& sx, float& sy,
                                           float m2, float s2, float sx2, float sy2) {
    float nm = fmaxf(m, m2);
    float c1 = __expf(m - nm);
    float c2 = __expf(m2 - nm);
    s  = s  * c1 + s2  * c2;
    sx = sx * c1 + sx2 * c2;
    sy = sy * c1 + sy2 * c2;
    m  = nm;
}

__global__ __launch_bounds__(512) void hl_batch_generic(
    const float* __restrict__ pred, const float* __restrict__ tgt,
    const float* __restrict__ poff, const float* __restrict__ tcoord,
    float* __restrict__ ws, int B, int H, int W) {
    const int b = blockIdx.x, tid = threadIdx.x;
    const int HW = H * W, n4 = HW >> 2;
    const float4* p4 = (const float4*)(pred + (size_t)b * HW);
    const float4* t4 = (const float4*)(tgt  + (size_t)b * HW);
    float m = -INFINITY, s = 0.f, sx = 0.f, sy = 0.f, hm = 0.f;
    for (int i = tid; i < n4; i += blockDim.x) {
        float4 pv = p4[i], tv = t4[i];
        int f = i << 2;
        float hf = (float)(f / W), wf = (float)(f % W);
        float pe[4] = {pv.x, pv.y, pv.z, pv.w};
        float te[4] = {tv.x, tv.y, tv.z, tv.w};
        for (int k = 0; k < 4; ++k) {
            float d = pe[k] - te[k];
            hm = fmaf(d * d, fmaf(WEIGHT_GAIN, te[k], 1.f), hm);
            float v = pe[k] * TEMP;
            float nm = fmaxf(m, v);
            float c = __expf(m - nm), e = __expf(v - nm);
            s = s * c + e; sx = sx * c + e * (wf + (float)k); sy = sy * c + e * hf;
            m = nm;
        }
    }
    for (int off = 32; off > 0; off >>= 1) {
        float mm = __shfl_xor(m, off), ss = __shfl_xor(s, off);
        float sxx = __shfl_xor(sx, off), syy = __shfl_xor(sy, off);
        sm_combine(m, s, sx, sy, mm, ss, sxx, syy);
        hm += __shfl_xor(hm, off);
    }
    __shared__ float red[8][5];
    int wave = tid >> 6, nwaves = blockDim.x >> 6;
    if ((tid & 63) == 0) {
        red[wave][0] = m; red[wave][1] = s; red[wave][2] = sx;
        red[wave][3] = sy; red[wave][4] = hm;
    }
    __syncthreads();
    if (tid == 0) {
        float M = red[0][0], S = red[0][1], SX = red[0][2], SY = red[0][3], HMs = red[0][4];
        for (int wv = 1; wv < nwaves; ++wv) {
            sm_combine(M, S, SX, SY, red[wv][0], red[wv][1], red[wv][2], red[wv][3]);
            HMs += red[wv][4];
        }
        float x = SX / S / (float)W, y = SY / S / (float)H;
        float dx = x + poff[2 * b] * OFFSET_SCALE - tcoord[2 * b];
        float dy = y + poff[2 * b + 1] * OFFSET_SCALE - tcoord[2 * b + 1];
        ws[b] = HMs;
        ws[B + b] = dx * dx + dy * dy;
    }
}

__global__ __launch_bounds__(256) void hl_final_generic(
    const float* __restrict__ ws, const float* __restrict__ poff,
    float* __restrict__ out, int B, int HW) {
    int t = threadIdx.x;
    float hm = 0.f, cd = 0.f, og = 0.f;
    for (int i = t; i < B; i += 256) { hm += ws[i]; cd += ws[B + i]; }
    for (int i = t; i < 2 * B; i += 256) { float v = poff[i]; og = fmaf(v, v, og); }
    __shared__ float r[256][3];
    r[t][0] = hm; r[t][1] = cd; r[t][2] = og;
    __syncthreads();
    for (int off = 128; off > 0; off >>= 1) {
        if (t < off) {
            r[t][0] += r[t + off][0]; r[t][1] += r[t + off][1]; r[t][2] += r[t + off][2];
        }
        __syncthreads();
    }
    if (t == 0) {
        float heatmap_loss = r[0][0] / ((float)B * (float)HW);
        float coord_loss   = r[0][1] / ((float)B * 2.f);
        float offset_reg   = r[0][2] / ((float)B * 2.f) * OFFSET_REG_W;
        out[0] = heatmap_loss + 2.0f * coord_loss + offset_reg;
        out[1] = heatmap_loss;
        out[2] = coord_loss;
    }
}

extern "C" void kernel_launch(void* const* d_in, const int* in_sizes, int n_in,
                              void* d_out, int out_size, void* d_ws, size_t ws_size,
                              hipStream_t stream) {
    const float* pred   = (const float*)d_in[0];
    const float* tgt    = (const float*)d_in[1];
    const float* poff   = (const float*)d_in[2];
    const float* tcoord = (const float*)d_in[3];
    int B  = in_sizes[2] / 2;
    int HW = in_sizes[0] / B;
    int W  = (int)(sqrt((double)HW) + 0.5);
    int H  = HW / W;

    constexpr int CHUNKS = 5, TPB = 256;
    size_t ws_need = (size_t)CHUNKS * B * sizeof(float4) + sizeof(int);

    if (W == 160 && H == 160 && ws_size >= ws_need) {
        float4* ws  = (float4*)d_ws;
        int*    cnt = (int*)((char*)d_ws + (size_t)CHUNKS * B * sizeof(float4));
        // zero the arrival counter each call (memset node in the captured graph)
        hipMemsetAsync(cnt, 0, sizeof(int), stream);
        hl_fused<160, 160, CHUNKS, TPB>
            <<<B * CHUNKS, TPB, 0, stream>>>(pred, tgt, poff, tcoord,
                                             (float*)d_out, ws, cnt, B);
    } else {
        float* ws = (float*)d_ws;
        hl_batch_generic<<<B, 512, 0, stream>>>(pred, tgt, poff, tcoord, ws, B, H, W);
        hl_final_generic<<<1, 256, 0, stream>>>(ws, poff, (float*)d_out, B, HW);
    }
}

// Round 5
// 50.865 us; speedup vs baseline: 2.0984x; 2.0984x over previous
//
#include <hip/hip_runtime.h>
#include <math.h>

#define TEMP 20.0f
#define OFFSET_SCALE 0.03f
#define OFFSET_REG_W 0.1f
#define WEIGHT_GAIN 5.0f
#define SM_SHIFT 90.0f   // fixed softmax shift: exp(20*p - 90); safe for p < ~8.9 sigma

// Device-coherent (agent-scope, cache-bypassing) scalar store/load.
// On gfx950 these lower to global_store/load with sc0 sc1 — visible device-wide
// WITHOUT the per-XCD L2 writeback/invalidate that __threadfence() costs.
__device__ __forceinline__ void agent_store(float* p, float v) {
    __hip_atomic_store(p, v, __ATOMIC_RELAXED, __HIP_MEMORY_SCOPE_AGENT);
}
__device__ __forceinline__ float agent_load(const float* p) {
    return __hip_atomic_load(p, __ATOMIC_RELAXED, __HIP_MEMORY_SCOPE_AGENT);
}

// ---------------- fused fast path: compile-time W,H, last-block finisher ----------------

template<int W, int H, int CHUNKS, int TPB>
__global__ __launch_bounds__(TPB) void hl_fused(
    const float* __restrict__ pred, const float* __restrict__ tgt,
    const float* __restrict__ poff, const float* __restrict__ tcoord,
    float* __restrict__ out, float* __restrict__ ws, int* __restrict__ cnt, int B) {
    constexpr int HW    = W * H;
    constexpr int CE    = HW / CHUNKS;      // elements per chunk (whole rows)
    constexpr int CF4   = CE / 4;
    constexpr int ITERS = CF4 / TPB;
    static_assert(CF4 % TPB == 0, "chunk must divide evenly");
    static_assert(CE % W == 0, "chunk must be whole rows");
    constexpr int NWAVES = TPB / 64;

    const int blk = blockIdx.x;
    const int b   = blk / CHUNKS;
    const int c   = blk % CHUNKS;
    const int tid = threadIdx.x;
    const float4* p4 = (const float4*)(pred + (size_t)b * HW + (size_t)c * CE);
    const float4* t4 = (const float4*)(tgt  + (size_t)b * HW + (size_t)c * CE);

    float s[4]  = {0.f, 0.f, 0.f, 0.f};
    float sx[4] = {0.f, 0.f, 0.f, 0.f};
    float sy[4] = {0.f, 0.f, 0.f, 0.f};
    float hm[4] = {0.f, 0.f, 0.f, 0.f};

#pragma unroll
    for (int it = 0; it < ITERS; ++it) {
        const int i = tid + it * TPB;
        float4 pv = p4[i];
        float4 tv = t4[i];
        const int f = i << 2;
        const float hf = (float)(c * (CE / W) + f / W);   // W constexpr -> magic multiply
        const float wf = (float)(f % W);
        float pe[4] = {pv.x, pv.y, pv.z, pv.w};
        float te[4] = {tv.x, tv.y, tv.z, tv.w};
#pragma unroll
        for (int k = 0; k < 4; ++k) {
            float d = pe[k] - te[k];
            hm[k] = fmaf(d * d, fmaf(WEIGHT_GAIN, te[k], 1.f), hm[k]);
            float e = __expf(fmaf(pe[k], TEMP, -SM_SHIFT));
            s[k] += e;
            sx[k] = fmaf(e, wf + (float)k, sx[k]);
            sy[k] = fmaf(e, hf, sy[k]);
        }
    }
    float S  = (s[0]  + s[1])  + (s[2]  + s[3]);
    float SX = (sx[0] + sx[1]) + (sx[2] + sx[3]);
    float SY = (sy[0] + sy[1]) + (sy[2] + sy[3]);
    float HM = (hm[0] + hm[1]) + (hm[2] + hm[3]);

#pragma unroll
    for (int off = 32; off > 0; off >>= 1) {
        S  += __shfl_xor(S,  off);
        SX += __shfl_xor(SX, off);
        SY += __shfl_xor(SY, off);
        HM += __shfl_xor(HM, off);
    }
    __shared__ float4 red[NWAVES];
    __shared__ int flag;
    const int wave = tid >> 6;
    if ((tid & 63) == 0) red[wave] = make_float4(S, SX, SY, HM);
    __syncthreads();
    if (tid == 0) {
        float4 a = red[0];
#pragma unroll
        for (int wv = 1; wv < NWAVES; ++wv) {
            float4 r = red[wv];
            a.x += r.x; a.y += r.y; a.z += r.z; a.w += r.w;
        }
        // device-coherent partial store (no cache flush), [chunk][batch] layout
        float* dst = ws + (size_t)(c * B + b) * 4;
        agent_store(dst + 0, a.x);
        agent_store(dst + 1, a.y);
        agent_store(dst + 2, a.z);
        agent_store(dst + 3, a.w);
        // drain the sc1 stores to the coherent point, THEN announce arrival
        asm volatile("s_waitcnt vmcnt(0)" ::: "memory");
        flag = __hip_atomic_fetch_add(cnt, 1, __ATOMIC_RELAXED,
                                      __HIP_MEMORY_SCOPE_AGENT);
    }
    __syncthreads();
    if (flag != (int)gridDim.x - 1) return;

    // ---- last block: all partials are at the coherent point; read them sc-coherent ----
    float HMt = 0.f, CD = 0.f, OG = 0.f;
    for (int bb = tid; bb < B; bb += TPB) {
        float Ss = 0.f, SXs = 0.f, SYs = 0.f, hms = 0.f;
#pragma unroll
        for (int cc = 0; cc < CHUNKS; ++cc) {
            const float* src = ws + (size_t)(cc * B + bb) * 4;
            Ss  += agent_load(src + 0);
            SXs += agent_load(src + 1);
            SYs += agent_load(src + 2);
            hms += agent_load(src + 3);
        }
        float x  = SXs / Ss / (float)W;
        float y  = SYs / Ss / (float)H;
        float o0 = poff[2 * bb], o1 = poff[2 * bb + 1];
        float dx = x + o0 * OFFSET_SCALE - tcoord[2 * bb];
        float dy = y + o1 * OFFSET_SCALE - tcoord[2 * bb + 1];
        CD += dx * dx + dy * dy;
        OG += o0 * o0 + o1 * o1;
        HMt += hms;
    }
#pragma unroll
    for (int off = 32; off > 0; off >>= 1) {
        HMt += __shfl_xor(HMt, off);
        CD  += __shfl_xor(CD,  off);
        OG  += __shfl_xor(OG,  off);
    }
    __shared__ float r3[NWAVES][3];
    if ((tid & 63) == 0) { r3[wave][0] = HMt; r3[wave][1] = CD; r3[wave][2] = OG; }
    __syncthreads();
    if (tid == 0) {
        float hmT = 0.f, cdT = 0.f, ogT = 0.f;
#pragma unroll
        for (int wv = 0; wv < NWAVES; ++wv) {
            hmT += r3[wv][0]; cdT += r3[wv][1]; ogT += r3[wv][2];
        }
        float HWf = (float)W * (float)H;
        float heatmap_loss = hmT / ((float)B * HWf);
        float coord_loss   = cdT / ((float)B * 2.f);
        float offset_reg   = ogT / ((float)B * 2.f) * OFFSET_REG_W;
        out[0] = heatmap_loss + 2.0f * coord_loss + offset_reg;
        out[1] = heatmap_loss;
        out[2] = coord_loss;
    }
}

// ---------------- generic fallback (online softmax, runtime shapes) ----------------

__device__ __forceinline__ void sm_combine(float& m, float& s, float& sx, float& sy,
                                           float m2, float s2, float sx2, float sy2) {
    float nm = fmaxf(m, m2);
    float c1 = __expf(m - nm);
    float c2 = __expf(m2 - nm);
    s  = s  * c1 + s2  * c2;
    sx = sx * c1 + sx2 * c2;
    sy = sy * c1 + sy2 * c2;
    m  = nm;
}

__global__ __launch_bounds__(512) void hl_batch_generic(
    const float* __restrict__ pred, const float* __restrict__ tgt,
    const float* __restrict__ poff, const float* __restrict__ tcoord,
    float* __restrict__ ws, int B, int H, int W) {
    const int b = blockIdx.x, tid = threadIdx.x;
    const int HW = H * W, n4 = HW >> 2;
    const float4* p4 = (const float4*)(pred + (size_t)b * HW);
    const float4* t4 = (const float4*)(tgt  + (size_t)b * HW);
    float m = -INFINITY, s = 0.f, sx = 0.f, sy = 0.f, hm = 0.f;
    for (int i = tid; i < n4; i += blockDim.x) {
        float4 pv = p4[i], tv = t4[i];
        int f = i << 2;
        float hf = (float)(f / W), wf = (float)(f % W);
        float pe[4] = {pv.x, pv.y, pv.z, pv.w};
        float te[4] = {tv.x, tv.y, tv.z, tv.w};
        for (int k = 0; k < 4; ++k) {
            float d = pe[k] - te[k];
            hm = fmaf(d * d, fmaf(WEIGHT_GAIN, te[k], 1.f), hm);
            float v = pe[k] * TEMP;
            float nm = fmaxf(m, v);
            float c = __expf(m - nm), e = __expf(v - nm);
            s = s * c + e; sx = sx * c + e * (wf + (float)k); sy = sy * c + e * hf;
            m = nm;
        }
    }
    for (int off = 32; off > 0; off >>= 1) {
        float mm = __shfl_xor(m, off), ss = __shfl_xor(s, off);
        float sxx = __shfl_xor(sx, off), syy = __shfl_xor(sy, off);
        sm_combine(m, s, sx, sy, mm, ss, sxx, syy);
        hm += __shfl_xor(hm, off);
    }
    __shared__ float red[8][5];
    int wave = tid >> 6, nwaves = blockDim.x >> 6;
    if ((tid & 63) == 0) {
        red[wave][0] = m; red[wave][1] = s; red[wave][2] = sx;
        red[wave][3] = sy; red[wave][4] = hm;
    }
    __syncthreads();
    if (tid == 0) {
        float M = red[0][0], S = red[0][1], SX = red[0][2], SY = red[0][3], HMs = red[0][4];
        for (int wv = 1; wv < nwaves; ++wv) {
            sm_combine(M, S, SX, SY, red[wv][0], red[wv][1], red[wv][2], red[wv][3]);
            HMs += red[wv][4];
        }
        float x = SX / S / (float)W, y = SY / S / (float)H;
        float dx = x + poff[2 * b] * OFFSET_SCALE - tcoord[2 * b];
        float dy = y + poff[2 * b + 1] * OFFSET_SCALE - tcoord[2 * b + 1];
        ws[b] = HMs;
        ws[B + b] = dx * dx + dy * dy;
    }
}

__global__ __launch_bounds__(256) void hl_final_generic(
    const float* __restrict__ ws, const float* __restrict__ poff,
    float* __restrict__ out, int B, int HW) {
    int t = threadIdx.x;
    float hm = 0.f, cd = 0.f, og = 0.f;
    for (int i = t; i < B; i += 256) { hm += ws[i]; cd += ws[B + i]; }
    for (int i = t; i < 2 * B; i += 256) { float v = poff[i]; og = fmaf(v, v, og); }
    __shared__ float r[256][3];
    r[t][0] = hm; r[t][1] = cd; r[t][2] = og;
    __syncthreads();
    for (int off = 128; off > 0; off >>= 1) {
        if (t < off) {
            r[t][0] += r[t + off][0]; r[t][1] += r[t + off][1]; r[t][2] += r[t + off][2];
        }
        __syncthreads();
    }
    if (t == 0) {
        float heatmap_loss = r[0][0] / ((float)B * (float)HW);
        float coord_loss   = r[0][1] / ((float)B * 2.f);
        float offset_reg   = r[0][2] / ((float)B * 2.f) * OFFSET_REG_W;
        out[0] = heatmap_loss + 2.0f * coord_loss + offset_reg;
        out[1] = heatmap_loss;
        out[2] = coord_loss;
    }
}

extern "C" void kernel_launch(void* const* d_in, const int* in_sizes, int n_in,
                              void* d_out, int out_size, void* d_ws, size_t ws_size,
                              hipStream_t stream) {
    const float* pred   = (const float*)d_in[0];
    const float* tgt    = (const float*)d_in[1];
    const float* poff   = (const float*)d_in[2];
    const float* tcoord = (const float*)d_in[3];
    int B  = in_sizes[2] / 2;
    int HW = in_sizes[0] / B;
    int W  = (int)(sqrt((double)HW) + 0.5);
    int H  = HW / W;

    constexpr int CHUNKS = 5, TPB = 256;
    size_t ws_need = (size_t)CHUNKS * B * 4 * sizeof(float) + sizeof(int);

    if (W == 160 && H == 160 && ws_size >= ws_need) {
        float* ws  = (float*)d_ws;
        int*   cnt = (int*)((char*)d_ws + (size_t)CHUNKS * B * 4 * sizeof(float));
        // zero the arrival counter each call (memset node in the captured graph)
        hipMemsetAsync(cnt, 0, sizeof(int), stream);
        hl_fused<160, 160, CHUNKS, TPB>
            <<<B * CHUNKS, TPB, 0, stream>>>(pred, tgt, poff, tcoord,
                                             (float*)d_out, ws, cnt, B);
    } else {
        float* ws = (float*)d_ws;
        hl_batch_generic<<<B, 512, 0, stream>>>(pred, tgt, poff, tcoord, ws, B, H, W);
        hl_final_generic<<<1, 256, 0, stream>>>(ws, poff, (float*)d_out, B, HW);
    }
}

// Round 6
// 23.965 us; speedup vs baseline: 4.4539x; 2.1225x over previous
//
#include <hip/hip_runtime.h>
#include <math.h>

#define TEMP 20.0f
#define OFFSET_SCALE 0.03f
#define OFFSET_REG_W 0.1f
#define WEIGHT_GAIN 5.0f
#define SM_SHIFT 90.0f   // fixed softmax shift: exp(20*p - 90); safe for p < ~8.9 sigma

// ---------------- fast path: compile-time W,H; all loads hoisted for max MLP ----------------

template<int W, int H, int CHUNKS, int TPB>
__global__ __launch_bounds__(TPB, 4) void hl_batch_fast(
    const float* __restrict__ pred, const float* __restrict__ tgt,
    float4* __restrict__ ws, int B) {
    constexpr int HW    = W * H;
    constexpr int CE    = HW / CHUNKS;      // elements per chunk (whole rows)
    constexpr int CF4   = CE / 4;
    constexpr int ITERS = CF4 / TPB;
    static_assert(CF4 % TPB == 0, "chunk must divide evenly");
    static_assert(CE % W == 0, "chunk must be whole rows");
    constexpr int NWAVES = TPB / 64;

    const int blk = blockIdx.x;
    const int b   = blk / CHUNKS;
    const int c   = blk % CHUNKS;
    const int tid = threadIdx.x;
    const float4* p4 = (const float4*)(pred + (size_t)b * HW + (size_t)c * CE);
    const float4* t4 = (const float4*)(tgt  + (size_t)b * HW + (size_t)c * CE);

    // Issue ALL global loads first -> ITERS*2 dwordx4 in flight per thread.
    float4 PV[ITERS], TV[ITERS];
#pragma unroll
    for (int it = 0; it < ITERS; ++it) {
        const int i = tid + it * TPB;
        PV[it] = p4[i];
        TV[it] = t4[i];
    }

    float s[4]  = {0.f, 0.f, 0.f, 0.f};
    float sx[4] = {0.f, 0.f, 0.f, 0.f};
    float sy[4] = {0.f, 0.f, 0.f, 0.f};
    float hm[4] = {0.f, 0.f, 0.f, 0.f};

#pragma unroll
    for (int it = 0; it < ITERS; ++it) {
        const int i = tid + it * TPB;
        const int f = i << 2;
        const float hf = (float)(c * (CE / W) + f / W);   // W constexpr -> magic multiply
        const float wf = (float)(f % W);
        float pe[4] = {PV[it].x, PV[it].y, PV[it].z, PV[it].w};
        float te[4] = {TV[it].x, TV[it].y, TV[it].z, TV[it].w};
#pragma unroll
        for (int k = 0; k < 4; ++k) {
            float d = pe[k] - te[k];
            hm[k] = fmaf(d * d, fmaf(WEIGHT_GAIN, te[k], 1.f), hm[k]);
            float e = __expf(fmaf(pe[k], TEMP, -SM_SHIFT));
            s[k] += e;
            sx[k] = fmaf(e, wf + (float)k, sx[k]);
            sy[k] = fmaf(e, hf, sy[k]);
        }
    }
    float S  = (s[0]  + s[1])  + (s[2]  + s[3]);
    float SX = (sx[0] + sx[1]) + (sx[2] + sx[3]);
    float SY = (sy[0] + sy[1]) + (sy[2] + sy[3]);
    float HM = (hm[0] + hm[1]) + (hm[2] + hm[3]);

#pragma unroll
    for (int off = 32; off > 0; off >>= 1) {
        S  += __shfl_xor(S,  off);
        SX += __shfl_xor(SX, off);
        SY += __shfl_xor(SY, off);
        HM += __shfl_xor(HM, off);
    }
    __shared__ float4 red[NWAVES];
    const int wave = tid >> 6;
    if ((tid & 63) == 0) red[wave] = make_float4(S, SX, SY, HM);
    __syncthreads();
    if (tid == 0) {
        float4 a = red[0];
#pragma unroll
        for (int wv = 1; wv < NWAVES; ++wv) {
            float4 r = red[wv];
            a.x += r.x; a.y += r.y; a.z += r.z; a.w += r.w;
        }
        ws[c * B + b] = a;   // [chunk][batch] -> coalesced float4 reads in finisher
    }
}

template<int CHUNKS>
__global__ __launch_bounds__(512) void hl_final_fast(
    const float4* __restrict__ ws, const float* __restrict__ poff,
    const float* __restrict__ tcoord, float* __restrict__ out,
    int B, int W, int H) {
    const int t = threadIdx.x;
    float HM = 0.f, CD = 0.f, OG = 0.f;
    for (int b = t; b < B; b += 512) {
        float S = 0.f, SX = 0.f, SY = 0.f, hm = 0.f;
#pragma unroll
        for (int c = 0; c < CHUNKS; ++c) {
            float4 r = ws[c * B + b];
            S += r.x; SX += r.y; SY += r.z; hm += r.w;
        }
        float x  = SX / S / (float)W;
        float y  = SY / S / (float)H;
        float2 po = ((const float2*)poff)[b];
        float2 tc = ((const float2*)tcoord)[b];
        float dx = x + po.x * OFFSET_SCALE - tc.x;
        float dy = y + po.y * OFFSET_SCALE - tc.y;
        CD += dx * dx + dy * dy;
        OG += po.x * po.x + po.y * po.y;
        HM += hm;
    }
#pragma unroll
    for (int off = 32; off > 0; off >>= 1) {
        HM += __shfl_xor(HM, off);
        CD += __shfl_xor(CD, off);
        OG += __shfl_xor(OG, off);
    }
    __shared__ float r3[8][3];
    const int wave = t >> 6;
    if ((t & 63) == 0) { r3[wave][0] = HM; r3[wave][1] = CD; r3[wave][2] = OG; }
    __syncthreads();
    if (t == 0) {
        float hmT = 0.f, cdT = 0.f, ogT = 0.f;
#pragma unroll
        for (int wv = 0; wv < 8; ++wv) { hmT += r3[wv][0]; cdT += r3[wv][1]; ogT += r3[wv][2]; }
        float HWf = (float)W * (float)H;
        float heatmap_loss = hmT / ((float)B * HWf);
        float coord_loss   = cdT / ((float)B * 2.f);
        float offset_reg   = ogT / ((float)B * 2.f) * OFFSET_REG_W;
        out[0] = heatmap_loss + 2.0f * coord_loss + offset_reg;
        out[1] = heatmap_loss;
        out[2] = coord_loss;
    }
}

// ---------------- generic fallback (online softmax, runtime shapes) ----------------

__device__ __forceinline__ void sm_combine(float& m, float& s, float& sx, float& sy,
                                           float m2, float s2, float sx2, float sy2) {
    float nm = fmaxf(m, m2);
    float c1 = __expf(m - nm);
    float c2 = __expf(m2 - nm);
    s  = s  * c1 + s2  * c2;
    sx = sx * c1 + sx2 * c2;
    sy = sy * c1 + sy2 * c2;
    m  = nm;
}

__global__ __launch_bounds__(512) void hl_batch_generic(
    const float* __restrict__ pred, const float* __restrict__ tgt,
    const float* __restrict__ poff, const float* __restrict__ tcoord,
    float* __restrict__ ws, int B, int H, int W) {
    const int b = blockIdx.x, tid = threadIdx.x;
    const int HW = H * W, n4 = HW >> 2;
    const float4* p4 = (const float4*)(pred + (size_t)b * HW);
    const float4* t4 = (const float4*)(tgt  + (size_t)b * HW);
    float m = -INFINITY, s = 0.f, sx = 0.f, sy = 0.f, hm = 0.f;
    for (int i = tid; i < n4; i += blockDim.x) {
        float4 pv = p4[i], tv = t4[i];
        int f = i << 2;
        float hf = (float)(f / W), wf = (float)(f % W);
        float pe[4] = {pv.x, pv.y, pv.z, pv.w};
        float te[4] = {tv.x, tv.y, tv.z, tv.w};
        for (int k = 0; k < 4; ++k) {
            float d = pe[k] - te[k];
            hm = fmaf(d * d, fmaf(WEIGHT_GAIN, te[k], 1.f), hm);
            float v = pe[k] * TEMP;
            float nm = fmaxf(m, v);
            float c = __expf(m - nm), e = __expf(v - nm);
            s = s * c + e; sx = sx * c + e * (wf + (float)k); sy = sy * c + e * hf;
            m = nm;
        }
    }
    for (int off = 32; off > 0; off >>= 1) {
        float mm = __shfl_xor(m, off), ss = __shfl_xor(s, off);
        float sxx = __shfl_xor(sx, off), syy = __shfl_xor(sy, off);
        sm_combine(m, s, sx, sy, mm, ss, sxx, syy);
        hm += __shfl_xor(hm, off);
    }
    __shared__ float red[8][5];
    int wave = tid >> 6, nwaves = blockDim.x >> 6;
    if ((tid & 63) == 0) {
        red[wave][0] = m; red[wave][1] = s; red[wave][2] = sx;
        red[wave][3] = sy; red[wave][4] = hm;
    }
    __syncthreads();
    if (tid == 0) {
        float M = red[0][0], S = red[0][1], SX = red[0][2], SY = red[0][3], HMs = red[0][4];
        for (int wv = 1; wv < nwaves; ++wv) {
            sm_combine(M, S, SX, SY, red[wv][0], red[wv][1], red[wv][2], red[wv][3]);
            HMs += red[wv][4];
        }
        float x = SX / S / (float)W, y = SY / S / (float)H;
        float dx = x + poff[2 * b] * OFFSET_SCALE - tcoord[2 * b];
        float dy = y + poff[2 * b + 1] * OFFSET_SCALE - tcoord[2 * b + 1];
        ws[b] = HMs;
        ws[B + b] = dx * dx + dy * dy;
    }
}

__global__ __launch_bounds__(256) void hl_final_generic(
    const float* __restrict__ ws, const float* __restrict__ poff,
    float* __restrict__ out, int B, int HW) {
    int t = threadIdx.x;
    float hm = 0.f, cd = 0.f, og = 0.f;
    for (int i = t; i < B; i += 256) { hm += ws[i]; cd += ws[B + i]; }
    for (int i = t; i < 2 * B; i += 256) { float v = poff[i]; og = fmaf(v, v, og); }
    __shared__ float r[256][3];
    r[t][0] = hm; r[t][1] = cd; r[t][2] = og;
    __syncthreads();
    for (int off = 128; off > 0; off >>= 1) {
        if (t < off) {
            r[t][0] += r[t + off][0]; r[t][1] += r[t + off][1]; r[t][2] += r[t + off][2];
        }
        __syncthreads();
    }
    if (t == 0) {
        float heatmap_loss = r[0][0] / ((float)B * (float)HW);
        float coord_loss   = r[0][1] / ((float)B * 2.f);
        float offset_reg   = r[0][2] / ((float)B * 2.f) * OFFSET_REG_W;
        out[0] = heatmap_loss + 2.0f * coord_loss + offset_reg;
        out[1] = heatmap_loss;
        out[2] = coord_loss;
    }
}

extern "C" void kernel_launch(void* const* d_in, const int* in_sizes, int n_in,
                              void* d_out, int out_size, void* d_ws, size_t ws_size,
                              hipStream_t stream) {
    const float* pred   = (const float*)d_in[0];
    const float* tgt    = (const float*)d_in[1];
    const float* poff   = (const float*)d_in[2];
    const float* tcoord = (const float*)d_in[3];
    int B  = in_sizes[2] / 2;
    int HW = in_sizes[0] / B;
    int W  = (int)(sqrt((double)HW) + 0.5);
    int H  = HW / W;

    if (W == 160 && H == 160 && ws_size >= (size_t)(5 * B) * sizeof(float4)) {
        constexpr int CHUNKS = 5, TPB = 256;
        hl_batch_fast<160, 160, CHUNKS, TPB>
            <<<B * CHUNKS, TPB, 0, stream>>>(pred, tgt, (float4*)d_ws, B);
        hl_final_fast<CHUNKS>
            <<<1, 512, 0, stream>>>((const float4*)d_ws, poff, tcoord,
                                    (float*)d_out, B, W, H);
    } else {
        float* ws = (float*)d_ws;
        hl_batch_generic<<<B, 512, 0, stream>>>(pred, tgt, poff, tcoord, ws, B, H, W);
        hl_final_generic<<<1, 256, 0, stream>>>(ws, poff, (float*)d_out, B, HW);
    }
}